// Round 2
// baseline (1475.686 us; speedup 1.0000x reference)
//
#include <hip/hip_runtime.h>
#include <hip/hip_bf16.h>
#include <hip/hip_fp16.h>

// ============================================================================
// ABSA LSTM on MI355X — Round 2: fp16 datapath + race-free double-buffered h
//
//  B=1024, T=80, V=50000, D=H=300, 4H=1200, C=3.
//  256 persistent blocks = 64 groups (16 batch rows) x 4 hidden-slices (75).
//  Per block: 4 waves, wave w = gate w, 5 N-tiles of 16 cols (80>=75).
//  Weights (Wx,Wh slice, fp16 MFMA-frag-packed) live in VGPRs all 80 steps:
//  100 frags = 400 VGPR -> launch_bounds(256,1), 1 wave/SIMD, 1 block/CU
//  (VGPR>256 forces CU-exclusivity => all 256 blocks co-resident => spin-sync
//  is deadlock-free by capacity).
//  h exchange: fp16 via global hbuf, PARITY DOUBLE-BUFFERED (write t&1, read
//  (t-1)&1; masked rows re-store frozen h) -> no fast-partner overwrite race.
//  Release: __syncthreads (drain stores) + tid0 __threadfence + atomic add.
//  Acquire: tid0 relaxed spin + __threadfence + __syncthreads.
// ============================================================================

typedef float    f32x4 __attribute__((ext_vector_type(4)));
typedef _Float16 f16;
typedef _Float16 f16x8 __attribute__((ext_vector_type(8)));

#define NB    1024
#define TT    80
#define NV    50000
#define ND    300
#define KP    320      // K padded to 10 tiles of 32
#define NKT   10
#define SL    75       // hidden cols per slice
#define NTPG  5        // 16-col N-tiles per gate (80 >= 75)
#define NTIL  20       // tiles per block = 4 gates * 5
#define TPB   256      // 4 waves
#define GRID  256

// ---- ws layout (bytes) ----
#define OFF_EMB   0                        // 50000*320*2 = 32,000,000
#define OFF_WHP   32000000                 // 4*20*10*512*2 = 819,200
#define OFF_WXP   32819200
#define OFF_HBUF  33638400                 // 2 parity * 1024*320*2 = 1,310,720
#define HBUF_SZ   (NB * KP)                // elements per parity buffer
#define OFF_HF32  34949120                 // 1024*300*4 = 1,228,800
#define OFF_FLAGS 36177920                 // 64 groups * 64B
#define WS_NEED   36182016

__global__ __launch_bounds__(256) void absa_prep_emb(
    const float* __restrict__ emb, f16* __restrict__ embb) {
  int i = blockIdx.x * 256 + threadIdx.x;           // 2,000,000 threads
  if (i >= NV * KP / 8) return;
  int flat = i * 8;
  int row  = flat / KP;
  int k    = flat - row * KP;
  f16x8 o;
  if (k + 7 < ND) {
    float4 a = *reinterpret_cast<const float4*>(emb + row * ND + k);
    float4 b = *reinterpret_cast<const float4*>(emb + row * ND + k + 4);
    o[0] = (f16)a.x; o[1] = (f16)a.y; o[2] = (f16)a.z; o[3] = (f16)a.w;
    o[4] = (f16)b.x; o[5] = (f16)b.y; o[6] = (f16)b.z; o[7] = (f16)b.w;
  } else {
#pragma unroll
    for (int e = 0; e < 8; ++e) {
      int kk = k + e;
      o[e] = (kk < ND) ? (f16)emb[row * ND + kk] : (f16)0.f;
    }
  }
  *reinterpret_cast<f16x8*>(embb + flat) = o;
}

// W f32[300][1200] -> [n<4][nt<20][kt<10][lane<64][e<8] fp16 frags.
// nt -> gate gi=nt/5, tile ti=nt%5; col = gi*300 + n*75 + ti*16 + (lane&15)
// k  = kt*32 + (lane>>4)*8 + e   (zero-pad k>=300 or local col>=75)
__global__ __launch_bounds__(256) void absa_prep_pack(
    const float* __restrict__ W, f16* __restrict__ out) {
  int idx = blockIdx.x * 256 + threadIdx.x;         // 409,600 threads
  if (idx >= 4 * NTIL * NKT * 512) return;
  int e    = idx & 7;
  int lane = (idx >> 3) & 63;
  int fid  = idx >> 9;
  int kt   = fid % NKT;
  int rem  = fid / NKT;
  int nt   = rem % NTIL;
  int n    = rem / NTIL;
  int gi   = nt / NTPG, ti = nt - gi * NTPG;
  int k    = kt * 32 + (lane >> 4) * 8 + e;
  int cc   = ti * 16 + (lane & 15);
  float v = 0.f;
  if (k < ND && cc < SL) v = W[k * 1200 + gi * 300 + n * SL + cc];
  out[idx] = (f16)v;
}

__device__ __forceinline__ float sigmoid_f(float x) { return 1.f / (1.f + __expf(-x)); }
__device__ __forceinline__ float tanh_f(float x) {
  x = fminf(15.f, fmaxf(-15.f, x));
  float e = __expf(2.f * x);
  return 1.f - 2.f / (e + 1.f);
}

__global__ __launch_bounds__(TPB, 1) void absa_lstm(
    const int* __restrict__ sent, const int* __restrict__ lens,
    const float* __restrict__ bvec,
    const f16* __restrict__ embb,
    const f16* __restrict__ whp, const f16* __restrict__ wxp,
    f16* __restrict__ hbuf, float* __restrict__ hf32,
    int* __restrict__ flags) {
  const int bid = blockIdx.x;
  const int s   = bid & 7;           // partners share s => same XCD heuristic
  const int q   = bid >> 3;
  const int n   = q & 3;             // hidden slice
  const int g   = s * 8 + (q >> 2);  // group (16 batch rows)

  const int tid = threadIdx.x;
  const int w   = tid >> 6;          // wave = gate
  const int l   = tid & 63;
  const int l15 = l & 15, lk = l >> 4;
  const int grow0 = g * 16;

  __shared__ float gates[4 * 80 * 20];   // [gate][col<80][row pad 20]
  __shared__ float c_lds[80 * 20];
  __shared__ float hf_lds[80 * 20];
  __shared__ float blds[4 * 80];
  __shared__ int   sent_lds[16 * TT];
  __shared__ int   len_lds[16];

  for (int i = tid; i < 16 * TT; i += TPB) sent_lds[i] = sent[g * (16 * TT) + i];
  if (tid < 16) len_lds[tid] = lens[grow0 + tid];
  for (int i = tid; i < 80 * 20; i += TPB) { c_lds[i] = 0.f; hf_lds[i] = 0.f; }
  for (int i = tid; i < 4 * 80; i += TPB) {
    int gi = i / 80, cc = i - gi * 80;
    blds[i] = (cc < SL) ? bvec[gi * 300 + n * SL + cc] : 0.f;
  }
  __syncthreads();

  int maxlen = 0;
#pragma unroll
  for (int r = 0; r < 16; ++r) maxlen = max(maxlen, len_lds[r]);

  // ---- register-resident fp16 weight fragments (live across all steps) ----
  f16x8 wh[NTPG][NKT], wx[NTPG][NKT];
#pragma unroll
  for (int j = 0; j < NTPG; ++j) {
#pragma unroll
    for (int kt = 0; kt < NKT; ++kt) {
      int off = ((n * NTIL + (w * NTPG + j)) * NKT + kt) * 512 + l * 8;
      wh[j][kt] = *reinterpret_cast<const f16x8*>(whp + off);
      wx[j][kt] = *reinterpret_cast<const f16x8*>(wxp + off);
    }
  }

  int gaddr[NTPG];
#pragma unroll
  for (int j = 0; j < NTPG; ++j)
    gaddr[j] = ((w * 80) + j * 16 + l15) * 20 + lk * 4;

  for (int t = 0; t < TT; ++t) {
    if (t >= maxlen) break;

    // ---- x-part: gates_x = x_t @ Wx (independent of h) ----
    f32x4 acc[NTPG];
#pragma unroll
    for (int j = 0; j < NTPG; ++j) acc[j] = (f32x4){0.f, 0.f, 0.f, 0.f};
    {
      f16x8 xa[NKT];
      const int srow = sent_lds[l15 * TT + t];
#pragma unroll
      for (int kt = 0; kt < NKT; ++kt)
        xa[kt] = *reinterpret_cast<const f16x8*>(embb + srow * KP + kt * 32 + lk * 8);
#pragma unroll
      for (int j = 0; j < NTPG; ++j)
#pragma unroll
        for (int kt = 0; kt < NKT; ++kt)
          acc[j] = __builtin_amdgcn_mfma_f32_16x16x32_f16(xa[kt], wx[j][kt], acc[j], 0, 0, 0);
    }

    // ---- acquire partners' h(t-1), then h-part ----
    if (t > 0) {
      if (tid == 0) {
        const int target = 4 * t;
        int spins = 0;
        while (__hip_atomic_load(flags + g * 16, __ATOMIC_RELAXED, __HIP_MEMORY_SCOPE_AGENT) < target
               && ++spins < (1 << 22)) {}
        __threadfence();   // acquire: inv L1/L2 so h reads are fresh cross-XCD
      }
      __syncthreads();

      const f16* hp = hbuf + ((t - 1) & 1) * HBUF_SZ + (grow0 + l15) * KP;
      f16x8 ha[NKT];
#pragma unroll
      for (int kt = 0; kt < NKT; ++kt)
        ha[kt] = *reinterpret_cast<const f16x8*>(hp + kt * 32 + lk * 8);
#pragma unroll
      for (int j = 0; j < NTPG; ++j)
#pragma unroll
        for (int kt = 0; kt < NKT; ++kt)
          acc[j] = __builtin_amdgcn_mfma_f32_16x16x32_f16(ha[kt], wh[j][kt], acc[j], 0, 0, 0);
    }

    // ---- C-tiles -> LDS ----
#pragma unroll
    for (int j = 0; j < NTPG; ++j)
      *reinterpret_cast<f32x4*>(&gates[gaddr[j]]) = acc[j];
    __syncthreads();

    // ---- elementwise; ALWAYS store h into current parity (masked rows too) --
    f16* hc = hbuf + (t & 1) * HBUF_SZ;
    for (int idx = tid; idx < 16 * SL; idx += TPB) {
      int row = idx & 15, cc = idx >> 4;
      int base = cc * 20 + row;
      float h;
      if (t < len_lds[row]) {
        float vi = gates[(0 * 80 + cc) * 20 + row] + blds[0 * 80 + cc];
        float vf = gates[(1 * 80 + cc) * 20 + row] + blds[1 * 80 + cc];
        float vg = gates[(2 * 80 + cc) * 20 + row] + blds[2 * 80 + cc];
        float vo = gates[(3 * 80 + cc) * 20 + row] + blds[3 * 80 + cc];
        float iv = sigmoid_f(vi), fv = sigmoid_f(vf), ov = sigmoid_f(vo);
        float gv = tanh_f(vg);
        float cn = fv * c_lds[base] + iv * gv;
        h = ov * tanh_f(cn);
        c_lds[base] = cn;
        hf_lds[base] = h;
      } else {
        h = hf_lds[base];
      }
      hc[(grow0 + row) * KP + n * SL + cc] = (f16)h;
    }
    __syncthreads();                  // drain h stores (vmcnt 0) block-wide
    if (tid == 0) {
      __threadfence();                // release: wb L2 -> agent-visible
      __hip_atomic_fetch_add(flags + g * 16, 1, __ATOMIC_RELAXED, __HIP_MEMORY_SCOPE_AGENT);
    }
  }

  // ---- final f32 h slice -> global ----
  for (int i = tid; i < 16 * SL; i += TPB) {
    int row = i & 15, cc = i >> 4;
    hf32[(grow0 + row) * ND + n * SL + cc] = hf_lds[cc * 20 + row];
  }
}

__global__ __launch_bounds__(256) void absa_logits(
    const float* __restrict__ hf32, const float* __restrict__ Wout,
    const float* __restrict__ bout, float* __restrict__ out) {
  int row = blockIdx.x * 256 + threadIdx.x;
  if (row >= NB) return;
  float s0 = bout[0], s1 = bout[1], s2 = bout[2];
  for (int k = 0; k < ND; ++k) {
    float h = hf32[row * ND + k];
    s0 += h * Wout[k * 3 + 0];
    s1 += h * Wout[k * 3 + 1];
    s2 += h * Wout[k * 3 + 2];
  }
  out[row * 3 + 0] = s0;
  out[row * 3 + 1] = s1;
  out[row * 3 + 2] = s2;
}

extern "C" void kernel_launch(void* const* d_in, const int* in_sizes, int n_in,
                              void* d_out, int out_size, void* d_ws, size_t ws_size,
                              hipStream_t stream) {
  const int*   sent = (const int*)d_in[0];
  const int*   lens = (const int*)d_in[1];
  const float* emb  = (const float*)d_in[2];
  const float* Wx   = (const float*)d_in[3];
  const float* Wh   = (const float*)d_in[4];
  const float* bv   = (const float*)d_in[5];
  const float* Wout = (const float*)d_in[6];
  const float* bout = (const float*)d_in[7];
  float* out = (float*)d_out;

  char* wsb = (char*)d_ws;
  f16*   embb  = (f16*)(wsb + OFF_EMB);
  f16*   whp   = (f16*)(wsb + OFF_WHP);
  f16*   wxp   = (f16*)(wsb + OFF_WXP);
  f16*   hbuf  = (f16*)(wsb + OFF_HBUF);
  float* hf32  = (float*)(wsb + OFF_HF32);
  int*   flags = (int*)(wsb + OFF_FLAGS);

  (void)hipMemsetAsync(hbuf, 0, 2 * HBUF_SZ * 2, stream);
  (void)hipMemsetAsync(flags, 0, 64 * 64, stream);

  absa_prep_emb <<<(NV * KP / 8 + 255) / 256, 256, 0, stream>>>(emb, embb);
  absa_prep_pack<<<4 * NTIL * NKT * 512 / 256, 256, 0, stream>>>(Wh, whp);
  absa_prep_pack<<<4 * NTIL * NKT * 512 / 256, 256, 0, stream>>>(Wx, wxp);
  absa_lstm     <<<GRID, TPB, 0, stream>>>(sent, lens, bv, embb, whp, wxp, hbuf, hf32, flags);
  absa_logits   <<<NB / 256, 256, 0, stream>>>(hf32, Wout, bout, out);
}

// Round 3
// 655.867 us; speedup vs baseline: 2.2500x; 2.2500x over previous
//
#include <hip/hip_runtime.h>
#include <hip/hip_fp16.h>

// ============================================================================
// ABSA LSTM on MI355X — Round 3: fence-free sc1 handshake
//
//  B=1024, T=80, V=50000, D=H=300, 4H=1200, C=3.
//  256 persistent blocks = 64 groups (16 batch rows) x 4 hidden-slices (75).
//  Per block: 4 waves, wave w = gate w, 5 N-tiles of 16 (80 cols >= 75).
//  fp16 Wx+Wh fragments register-resident (~400 V/AGPRs) -> 1 block/CU
//  -> all 256 blocks co-resident -> spin sync deadlock-free by capacity.
//
//  Round-2 lesson (rocprof): 17.3us/step, MfmaUtil 3.6% — the per-step
//  __threadfence pair (buffer_wbl2 + buffer_inv, whole-L2 writeback/inv
//  per block per step) was ~96% of runtime. Round 3 removes ALL fences:
//  h data moves via relaxed AGENT-scope atomics (sc1 -> L3 coherence point):
//    producer: u32 atomic stores of h pairs -> vmcnt(0) drain at barrier ->
//              relaxed agent atomic_fetch_add flag
//    consumer: all-thread relaxed spin on flag -> u64 atomic loads of h frags
//  hbuf physical layout: [parity][row][4 slices x 80] (8B-aligned chunks);
//  Wh packed against that k-mapping. Bias folded into k=300 row of x-GEMM
//  (embb[.,300]=1.0, Wx pack row 300 = b). sigmoid/tanh via v_exp+v_rcp.
// ============================================================================

typedef float    f32x4 __attribute__((ext_vector_type(4)));
typedef _Float16 f16;
typedef _Float16 f16x8 __attribute__((ext_vector_type(8)));
typedef unsigned long long u64;
typedef unsigned int       u32;

#define NB    1024
#define TT    80
#define NV    50000
#define ND    300
#define KP    320      // padded K: 10 tiles of 32 (covers 300 real + bias row 300)
#define NKT   10
#define SL    75       // hidden cols per slice
#define SLP   80       // physical slice stride inside hbuf row (4*80 = 320 = KP)
#define NTPG  5        // 16-col N-tiles per gate per block
#define NTIL  20       // 4 gates * 5
#define TPB   256      // 4 waves
#define GRID  256

// ---- ws layout (bytes) ----
#define OFF_EMB   0                        // 50000*320*2 = 32,000,000
#define OFF_WHP   32000000                 // 4*20*10*512*2 = 819,200
#define OFF_WXP   32819200
#define OFF_HBUF  33638400                 // 2 parity * 1024*320*2
#define HBUF_SZ   (NB * KP)
#define OFF_HF32  34949120                 // 1024*300*4
#define OFF_FLAGS 36177920                 // 64 groups * 64B
#define WS_NEED   36182016

// emb f32[50000][300] -> fp16 [50000][320]; col 300 = 1.0 (bias row), >300 = 0
__global__ __launch_bounds__(256) void absa_prep_emb(
    const float* __restrict__ emb, f16* __restrict__ embb) {
  int i = blockIdx.x * 256 + threadIdx.x;
  if (i >= NV * KP / 8) return;
  int flat = i * 8;
  int row  = flat / KP;
  int k    = flat - row * KP;
  f16x8 o;
  if (k + 7 < ND) {
    float4 a = *reinterpret_cast<const float4*>(emb + row * ND + k);
    float4 b = *reinterpret_cast<const float4*>(emb + row * ND + k + 4);
    o[0] = (f16)a.x; o[1] = (f16)a.y; o[2] = (f16)a.z; o[3] = (f16)a.w;
    o[4] = (f16)b.x; o[5] = (f16)b.y; o[6] = (f16)b.z; o[7] = (f16)b.w;
  } else {
#pragma unroll
    for (int e = 0; e < 8; ++e) {
      int kk = k + e;
      float v = (kk < ND) ? emb[row * ND + kk] : (kk == ND ? 1.0f : 0.0f);
      o[e] = (f16)v;
    }
  }
  *reinterpret_cast<f16x8*>(embb + flat) = o;
}

// W f32[300][1200] (+bias for mode 0) -> [n<4][nt<20][kt<10][lane<64][e<8] fp16
// col = gi*300 + n*75 + ti*16 + (lane&15)  (zero if local col >= 75)
// mode 0 (Wx): k-logical = k-physical; k==300 -> bias[col]; k>300 -> 0
// mode 1 (Wh): k-physical in 4x80 blocks; klog = (k/80)*75 + k%80, pad if %80>=75
__global__ __launch_bounds__(256) void absa_prep_pack(
    const float* __restrict__ W, const float* __restrict__ bias,
    f16* __restrict__ out, int mode) {
  int idx = blockIdx.x * 256 + threadIdx.x;
  if (idx >= 4 * NTIL * NKT * 512) return;
  int e    = idx & 7;
  int lane = (idx >> 3) & 63;
  int fid  = idx >> 9;
  int kt   = fid % NKT;
  int rem  = fid / NKT;
  int nt   = rem % NTIL;
  int n    = rem / NTIL;
  int gi   = nt / NTPG, ti = nt - gi * NTPG;
  int k    = kt * 32 + (lane >> 4) * 8 + e;
  int cc   = ti * 16 + (lane & 15);
  float v = 0.f;
  if (cc < SL) {
    int col = gi * 300 + n * SL + cc;
    if (mode == 0) {
      if (k < ND)       v = W[k * 1200 + col];
      else if (k == ND) v = bias[col];
    } else {
      int kl = k % SLP, n2 = k / SLP;
      if (kl < SL)      v = W[(n2 * SL + kl) * 1200 + col];
    }
  }
  out[idx] = (f16)v;
}

__device__ __forceinline__ float sigf(float x) {
  return __builtin_amdgcn_rcpf(1.f + __builtin_amdgcn_exp2f(-1.44269504f * x));
}
__device__ __forceinline__ float tanhf_(float x) {
  float xx = fminf(15.f, fmaxf(-15.f, x));
  return 1.f - 2.f * __builtin_amdgcn_rcpf(1.f + __builtin_amdgcn_exp2f(2.88539008f * xx));
}

__global__ __launch_bounds__(TPB, 1) void absa_lstm(
    const int* __restrict__ sent, const int* __restrict__ lens,
    const f16* __restrict__ embb,
    const f16* __restrict__ whp, const f16* __restrict__ wxp,
    f16* __restrict__ hbuf, float* __restrict__ hf32,
    int* __restrict__ flags) {
  const int bid = blockIdx.x;
  const int s   = bid & 7;           // partners share s => same XCD heuristic
  const int q   = bid >> 3;
  const int n   = q & 3;             // hidden slice
  const int g   = s * 8 + (q >> 2);  // batch group (16 rows)

  const int tid = threadIdx.x;
  const int w   = tid >> 6;          // wave = gate
  const int l   = tid & 63;
  const int l15 = l & 15, lk = l >> 4;
  const int grow0 = g * 16;

  __shared__ float gates[4 * 80 * 20];   // [gate][col<80][row pad 20]
  __shared__ float c_lds[80 * 20];
  __shared__ float hf_lds[80 * 20];
  __shared__ int   sent_lds[16 * TT];
  __shared__ int   len_lds[16];

  for (int i = tid; i < 16 * TT; i += TPB) sent_lds[i] = sent[g * (16 * TT) + i];
  if (tid < 16) len_lds[tid] = lens[grow0 + tid];
  for (int i = tid; i < 80 * 20; i += TPB) { c_lds[i] = 0.f; hf_lds[i] = 0.f; }
  __syncthreads();

  int maxlen = 0;
#pragma unroll
  for (int r = 0; r < 16; ++r) maxlen = max(maxlen, len_lds[r]);

  // ---- register-resident fp16 weight fragments ----
  f16x8 wh[NTPG][NKT], wx[NTPG][NKT];
#pragma unroll
  for (int j = 0; j < NTPG; ++j) {
#pragma unroll
    for (int kt = 0; kt < NKT; ++kt) {
      int off = ((n * NTIL + (w * NTPG + j)) * NKT + kt) * 512 + l * 8;
      wh[j][kt] = *reinterpret_cast<const f16x8*>(whp + off);
      wx[j][kt] = *reinterpret_cast<const f16x8*>(wxp + off);
    }
  }

  int gaddr[NTPG];
#pragma unroll
  for (int j = 0; j < NTPG; ++j)
    gaddr[j] = ((w * 80) + j * 16 + l15) * 20 + lk * 4;

  int* const flagp = flags + g * 16;

  for (int t = 0; t < TT; ++t) {
    if (t >= maxlen) break;

    // ---- x-part: overlaps partners finishing step t-1 ----
    f32x4 acc[NTPG];
#pragma unroll
    for (int j = 0; j < NTPG; ++j) acc[j] = (f32x4){0.f, 0.f, 0.f, 0.f};
    {
      f16x8 xa[NKT];
      const int srow = sent_lds[l15 * TT + t];
#pragma unroll
      for (int kt = 0; kt < NKT; ++kt)
        xa[kt] = *reinterpret_cast<const f16x8*>(embb + srow * KP + kt * 32 + lk * 8);
#pragma unroll
      for (int j = 0; j < NTPG; ++j)
#pragma unroll
        for (int kt = 0; kt < NKT; ++kt)
          acc[j] = __builtin_amdgcn_mfma_f32_16x16x32_f16(xa[kt], wx[j][kt], acc[j], 0, 0, 0);
    }

    // ---- acquire h(t-1): all-thread relaxed spin, then sc1 loads ----
    if (t > 0) {
      {
        const int target = 4 * t;
        int spins = 0;
        while (__hip_atomic_load(flagp, __ATOMIC_RELAXED, __HIP_MEMORY_SCOPE_AGENT) < target
               && ++spins < (1 << 22))
          __builtin_amdgcn_s_sleep(1);
      }
      const f16* hp = hbuf + ((t - 1) & 1) * HBUF_SZ + (grow0 + l15) * KP;
      f16x8 ha[NKT];
#pragma unroll
      for (int kt = 0; kt < NKT; ++kt) {
        union { u64 qd[2]; f16x8 v; } u;
        const u64* p = reinterpret_cast<const u64*>(hp + kt * 32 + lk * 8);
        u.qd[0] = __hip_atomic_load(p,     __ATOMIC_RELAXED, __HIP_MEMORY_SCOPE_AGENT);
        u.qd[1] = __hip_atomic_load(p + 1, __ATOMIC_RELAXED, __HIP_MEMORY_SCOPE_AGENT);
        ha[kt] = u.v;
      }
#pragma unroll
      for (int j = 0; j < NTPG; ++j)
#pragma unroll
        for (int kt = 0; kt < NKT; ++kt)
          acc[j] = __builtin_amdgcn_mfma_f32_16x16x32_f16(ha[kt], wh[j][kt], acc[j], 0, 0, 0);
    }

    // ---- C-tiles -> LDS ----
#pragma unroll
    for (int j = 0; j < NTPG; ++j)
      *reinterpret_cast<f32x4*>(&gates[gaddr[j]]) = acc[j];
    __syncthreads();

    // ---- elementwise + packed sc1 h stores (bias already in gates) ----
    f16* hc = hbuf + (t & 1) * HBUF_SZ;
    for (int i = tid; i < 16 * 38; i += TPB) {     // 608 items: (row, col-pair)
      int row = i & 15;
      int cc0 = (i >> 4) * 2;                      // 0,2,...,74
      float hv[2];
#pragma unroll
      for (int e = 0; e < 2; ++e) {
        int cc = cc0 + e;
        float h = 0.f;
        if (cc < SL) {
          int base = cc * 20 + row;
          if (t < len_lds[row]) {
            float vi = gates[(0 * 80 + cc) * 20 + row];
            float vf = gates[(1 * 80 + cc) * 20 + row];
            float vg = gates[(2 * 80 + cc) * 20 + row];
            float vo = gates[(3 * 80 + cc) * 20 + row];
            float iv = sigf(vi), fv = sigf(vf), ov = sigf(vo);
            float gv = tanhf_(vg);
            float cn = fv * c_lds[base] + iv * gv;
            h = ov * tanhf_(cn);
            c_lds[base] = cn;
            hf_lds[base] = h;
          } else {
            h = hf_lds[base];
          }
        }
        hv[e] = h;
      }
      union { f16 h2[2]; u32 uu; } pu;
      pu.h2[0] = (f16)hv[0]; pu.h2[1] = (f16)hv[1];
      u32* dst = reinterpret_cast<u32*>(hc + (grow0 + row) * KP + n * SLP + cc0);
      __hip_atomic_store(dst, pu.uu, __ATOMIC_RELAXED, __HIP_MEMORY_SCOPE_AGENT);
    }
    __syncthreads();       // compiler drains vmcnt(0) for ALL waves before barrier
    if (tid == 0)
      __hip_atomic_fetch_add(flagp, 1, __ATOMIC_RELAXED, __HIP_MEMORY_SCOPE_AGENT);
  }

  // ---- final f32 h slice -> global ----
  for (int i = tid; i < 16 * SL; i += TPB) {
    int row = i & 15, cc = i >> 4;
    hf32[(grow0 + row) * ND + n * SL + cc] = hf_lds[cc * 20 + row];
  }
}

__global__ __launch_bounds__(256) void absa_logits(
    const float* __restrict__ hf32, const float* __restrict__ Wout,
    const float* __restrict__ bout, float* __restrict__ out) {
  int row = blockIdx.x * 256 + threadIdx.x;
  if (row >= NB) return;
  float s0 = bout[0], s1 = bout[1], s2 = bout[2];
  for (int k = 0; k < ND; ++k) {
    float h = hf32[row * ND + k];
    s0 += h * Wout[k * 3 + 0];
    s1 += h * Wout[k * 3 + 1];
    s2 += h * Wout[k * 3 + 2];
  }
  out[row * 3 + 0] = s0;
  out[row * 3 + 1] = s1;
  out[row * 3 + 2] = s2;
}

extern "C" void kernel_launch(void* const* d_in, const int* in_sizes, int n_in,
                              void* d_out, int out_size, void* d_ws, size_t ws_size,
                              hipStream_t stream) {
  const int*   sent = (const int*)d_in[0];
  const int*   lens = (const int*)d_in[1];
  const float* emb  = (const float*)d_in[2];
  const float* Wx   = (const float*)d_in[3];
  const float* Wh   = (const float*)d_in[4];
  const float* bv   = (const float*)d_in[5];
  const float* Wout = (const float*)d_in[6];
  const float* bout = (const float*)d_in[7];
  float* out = (float*)d_out;

  char* wsb = (char*)d_ws;
  f16*   embb  = (f16*)(wsb + OFF_EMB);
  f16*   whp   = (f16*)(wsb + OFF_WHP);
  f16*   wxp   = (f16*)(wsb + OFF_WXP);
  f16*   hbuf  = (f16*)(wsb + OFF_HBUF);
  float* hf32  = (float*)(wsb + OFF_HF32);
  int*   flags = (int*)(wsb + OFF_FLAGS);

  (void)hipMemsetAsync(hbuf, 0, 2 * HBUF_SZ * 2, stream);
  (void)hipMemsetAsync(flags, 0, 64 * 64, stream);

  absa_prep_emb <<<(NV * KP / 8 + 255) / 256, 256, 0, stream>>>(emb, embb);
  absa_prep_pack<<<4 * NTIL * NKT * 512 / 256, 256, 0, stream>>>(Wh, bv, whp, 1);
  absa_prep_pack<<<4 * NTIL * NKT * 512 / 256, 256, 0, stream>>>(Wx, bv, wxp, 0);
  absa_lstm     <<<GRID, TPB, 0, stream>>>(sent, lens, embb, whp, wxp, hbuf, hf32, flags);
  absa_logits   <<<NB / 256, 256, 0, stream>>>(hf32, Wout, bout, out);
}